// Round 10
// baseline (217.194 us; speedup 1.0000x reference)
//
#include <hip/hip_runtime.h>
#include <math.h>

typedef unsigned short u16;
typedef unsigned int u32;
typedef __bf16 bf16x8 __attribute__((ext_vector_type(8)));
typedef float f32x4 __attribute__((ext_vector_type(4)));
typedef unsigned short u16x8 __attribute__((ext_vector_type(8)));
typedef unsigned int u32x2 __attribute__((ext_vector_type(2)));

static __device__ __forceinline__ u16 f2bf(float f) {
  unsigned int u = __builtin_bit_cast(unsigned int, f);
  u = (u + 0x7FFFu + ((u >> 16) & 1u)) >> 16;
  return (u16)u;
}
static __device__ __forceinline__ float bf2f(u16 u) {
  unsigned int x = ((unsigned int)u) << 16;
  return __builtin_bit_cast(float, x);
}
static __device__ __forceinline__ u16 f2bfh(float f) {
  __bf16 b = (__bf16)f;
  return __builtin_bit_cast(u16, b);
}
static __device__ __forceinline__ void gll16(const u16* g, u16* l) {
  __builtin_amdgcn_global_load_lds((const __attribute__((address_space(1))) u32*)g,
                                   (__attribute__((address_space(3))) u32*)l, 16, 0, 0);
}

// ---------------- fused f32 -> bf16 convert for two buffers ----------------
__global__ __launch_bounds__(256) void cvt2_bf16(const float* __restrict__ a, u16* __restrict__ da, int n4a,
                                                 const float* __restrict__ b, u16* __restrict__ db, int n4b) {
  int idx = blockIdx.x * 256 + threadIdx.x;
  const float* src; u16* dst; int i;
  if (idx < n4a) { src = a; dst = da; i = idx; }
  else { i = idx - n4a; if (i >= n4b) return; src = b; dst = db; }
  float4 v = ((const float4*)src)[i];
  ushort4 r;
  r.x = f2bf(v.x); r.y = f2bf(v.y); r.z = f2bf(v.z); r.w = f2bf(v.w);
  ((ushort4*)dst)[i] = r;
}

// ---------------- bf16 NT GEMM, m97 structure: gll16 staging, linear LDS + swizzled src ----
// 128x128 tile, BK=32, 256 threads (4 waves, each 64x64).
__global__ __launch_bounds__(256) void gemm_nt(const u16* __restrict__ A, const u16* __restrict__ B,
                                               float* __restrict__ C, int M, int N, int K) {
  __shared__ __align__(16) u16 sA[128 * 32];
  __shared__ __align__(16) u16 sB[128 * 32];
  const int tid = threadIdx.x;
  const int w = tid >> 6, lane = tid & 63, l15 = lane & 15;
  const int m0 = blockIdx.x * 128, n0 = blockIdx.y * 128;
  const int wm = (w >> 1) * 64, wn = (w & 1) * 64;

  f32x4 acc[4][4] = {};

  const int pb0 = w * 1024 + lane * 16;
  int srow[2], scol[2];
#pragma unroll
  for (int i = 0; i < 2; ++i) {
    int p = pb0 + i * 4096;
    int row = p >> 6, oo = p & 63;
    int ol = oo ^ (((row >> 1) & 3) << 4);
    srow[i] = row; scol[i] = ol >> 1;
  }
  int aoff[4], boff[4];
  const int kb = (lane >> 4) * 16;
#pragma unroll
  for (int m = 0; m < 4; ++m) {
    int r = wm + m * 16 + l15;
    aoff[m] = r * 64 + (kb ^ (((r >> 1) & 3) << 4));
  }
#pragma unroll
  for (int n = 0; n < 4; ++n) {
    int r = wn + n * 16 + l15;
    boff[n] = r * 64 + (kb ^ (((r >> 1) & 3) << 4));
  }

  for (int k0 = 0; k0 < K; k0 += 32) {
#pragma unroll
    for (int i = 0; i < 2; ++i) {
      int p = pb0 + i * 4096;
      gll16(A + (size_t)(m0 + srow[i]) * K + k0 + scol[i], (u16*)((char*)sA + p));
      gll16(B + (size_t)(n0 + srow[i]) * K + k0 + scol[i], (u16*)((char*)sB + p));
    }
    __syncthreads();
    bf16x8 af[4], bfr[4];
#pragma unroll
    for (int m = 0; m < 4; ++m) af[m] = *(const bf16x8*)((const char*)sA + aoff[m]);
#pragma unroll
    for (int n = 0; n < 4; ++n) bfr[n] = *(const bf16x8*)((const char*)sB + boff[n]);
#pragma unroll
    for (int m = 0; m < 4; ++m)
#pragma unroll
      for (int n = 0; n < 4; ++n)
        acc[m][n] = __builtin_amdgcn_mfma_f32_16x16x32_bf16(af[m], bfr[n], acc[m][n], 0, 0, 0);
    __syncthreads();
  }

#pragma unroll
  for (int m = 0; m < 4; ++m)
#pragma unroll
    for (int i = 0; i < 4; ++i) {
      int gr = m0 + wm + m * 16 + (lane >> 4) * 4 + i;
      float* crow = C + (size_t)gr * N + n0 + wn + l15;
#pragma unroll
      for (int n = 0; n < 4; ++n) crow[n * 16] = acc[m][n][i];
    }
}

// ---------------- RMSNorm + RoPE + V cast + gate ----------------
#define QSCALE 0.18033688011112042f
__global__ __launch_bounds__(256) void norm_rope_gate(const float* __restrict__ qkv, const float* __restrict__ x,
                                                      const float* __restrict__ qw, const float* __restrict__ kw,
                                                      const float* __restrict__ gw,
                                                      u16* __restrict__ Q, u16* __restrict__ Kd,
                                                      u16* __restrict__ V, float* __restrict__ gate) {
  const int t = blockIdx.x * 4 + (threadIdx.x >> 6);
  const int lane = threadIdx.x & 63;
  const int b = t >> 11, s = t & 2047;
  const float* base = qkv + (size_t)t * 1536;
  const int ri = lane >> 1;
  float sn, cs;
  sincosf((float)s * expf(-(float)ri * (9.21034037198f / 32.0f)), &sn, &cs);
  const float qwl = qw[lane], kwl = kw[lane];

  for (int hh = 0; hh < 16; ++hh) {
    float v = base[hh * 64 + lane];
    float ss = v * v;
#pragma unroll
    for (int off = 32; off >= 1; off >>= 1) ss += __shfl_xor(ss, off);
    float r = rsqrtf(ss * (1.0f / 64.0f) + 1.1920929e-7f);
    float xn = v * r * qwl;
    float p = __shfl_xor(xn, 1);
    float outv = ((lane & 1) == 0) ? (xn * cs - p * sn) : (xn * cs + p * sn);
    Q[((size_t)(b * 16 + hh) * 2048 + s) * 64 + lane] = f2bf(outv * QSCALE);
  }
  for (int hh = 0; hh < 4; ++hh) {
    float v = base[1024 + hh * 64 + lane];
    float ss = v * v;
#pragma unroll
    for (int off = 32; off >= 1; off >>= 1) ss += __shfl_xor(ss, off);
    float r = rsqrtf(ss * (1.0f / 64.0f) + 1.1920929e-7f);
    float xn = v * r * kwl;
    float p = __shfl_xor(xn, 1);
    float outv = ((lane & 1) == 0) ? (xn * cs - p * sn) : (xn * cs + p * sn);
    Kd[((size_t)(b * 4 + hh) * 2048 + s) * 64 + lane] = f2bf(outv);
    V[((size_t)(b * 4 + hh) * 2048 + s) * 64 + lane] = f2bf(base[1280 + hh * 64 + lane]);
  }
  if (lane < 16) {
    float g = 0.f;
#pragma unroll
    for (int j = 0; j < 12; ++j) g += x[(size_t)t * 1024 + j] * gw[lane * 12 + j];
    gate[(size_t)t * 16 + lane] = 1.0f / (1.0f + __expf(-g));
  }
}

// ---------------- V transpose: [bh][s][d] -> [bh][d][s] ----------------
__global__ __launch_bounds__(256) void transpose_v64(const u16* __restrict__ V, u16* __restrict__ Vt) {
  __shared__ __align__(16) u16 tile[64][72];
  const int st = blockIdx.x, bh = blockIdx.y;
  const u16* src = V + ((size_t)bh * 2048 + st * 64) * 64;
  u16* dst = Vt + (size_t)bh * 64 * 2048 + st * 64;
  const int t = threadIdx.x;
  const int r = t >> 2, c0 = (t & 3) * 16;
#pragma unroll
  for (int j = 0; j < 2; ++j)
    *(u16x8*)&tile[r][c0 + j * 8] = *(const u16x8*)&src[(size_t)r * 64 + c0 + j * 8];
  __syncthreads();
  u16 tmp[16];
#pragma unroll
  for (int j = 0; j < 16; ++j) tmp[j] = tile[c0 + j][r];
#pragma unroll
  for (int j = 0; j < 2; ++j)
    *(u16x8*)&dst[(size_t)r * 2048 + c0 + j * 8] = *(const u16x8*)&tmp[j * 8];
}

// ---------------- Flash attention: paired q-tiles + KV-parity split, swapped QK^T ------
// grid (16, B*H, 2). LDS = 32768 B (sK 8K + sV 8K + sP 16K) and VGPR<=102 via
// __launch_bounds__(256,5): targets 4-5 blocks/CU residency. Single-buffered K/V with
// T14 reg-prefetch, 2 barriers/tile (write-then-compute). Phased fragment reads:
// kf (QK phase) and vf (PV phase) never coexist -> lower peak VGPR.
__global__ __launch_bounds__(256, 5) void attn_fwd_pair(const u16* __restrict__ Q, const u16* __restrict__ Kg,
                                                        const u16* __restrict__ Vt,
                                                        u16* __restrict__ accP, float* __restrict__ lP) {
  __shared__ __align__(16) u16 sK[64 * 64];      // K[kv][d], swizzled
  __shared__ __align__(16) u16 sV[64 * 64];      // Vt[d][kv], swizzled
  __shared__ __align__(16) u16 sP[2][4][16 * 64]; // per-stream per-wave P[q][kv], swizzled

  const int tid = threadIdx.x;
  const int w = tid >> 6, lane = tid & 63;
  const int l15 = lane & 15, lg = lane >> 4;
  const int qiA = blockIdx.x;          // 0..15
  const int qiB = 31 - qiA;            // 31..16
  const int z = blockIdx.z;
  const int bh = blockIdx.y, b = bh >> 4, h = bh & 15, kvh = h >> 2;

  const u16* Qp = Q + (size_t)(b * 16 + h) * 2048 * 64;
  const u16* Kp = Kg + (size_t)(b * 4 + kvh) * 2048 * 64;
  const u16* Vp = Vt + (size_t)(b * 4 + kvh) * 64 * 2048;

  const int q0s[2] = {qiA * 64, qiB * 64};
  bf16x8 qa[2][2];
#pragma unroll
  for (int s = 0; s < 2; ++s) {
    const u16* qrow = Qp + (size_t)(q0s[s] + w * 16 + l15) * 64 + lg * 8;
    qa[s][0] = *(const bf16x8*)qrow;
    qa[s][1] = *(const bf16x8*)(qrow + 32);
  }

  f32x4 acc[2][4] = {};
  float l_s[2] = {0.f, 0.f};

  // staging addresses: global linear; LDS swizzled (T2: byte ^= (row&7)<<4, both sides)
  const int srw = tid >> 2;                       // 0..63 rows
  const int scb = (tid & 3) * 32;                 // byte col base in row (128 B rows)
  const int swzS = (srw & 7) << 4;
  const int st0 = srw * 128 + (scb ^ swzS);
  const int st1 = srw * 128 + ((scb + 16) ^ swzS);
  const u16* kgp = Kp + (size_t)srw * 64 + (tid & 3) * 16;
  const u16* vgp = Vp + (size_t)srw * 2048 + (tid & 3) * 16;

  // fragment read byte offsets
  const int swzF = (l15 & 7) << 4;
  const int fo0 = (lg * 16) ^ swzF;        // k-half 0
  const int fo1 = (64 + lg * 16) ^ swzF;   // k-half 1
  const int swzP = swzF;
  char* prow0 = (char*)sP[0][w] + l15 * 128;
  char* prow1 = (char*)sP[1][w] + l15 * 128;

  // prologue: load tile z into regs
  u16x8 kr0 = *(const u16x8*)(kgp + (size_t)z * 64 * 64), kr1 = *(const u16x8*)(kgp + (size_t)z * 64 * 64 + 8);
  u16x8 vr0 = *(const u16x8*)(vgp + z * 64),              vr1 = *(const u16x8*)(vgp + z * 64 + 8);

  for (int t = z; t <= qiB; t += 2) {
    __syncthreads();   // all waves done reading previous tile
    *(u16x8*)((char*)sK + st0) = kr0; *(u16x8*)((char*)sK + st1) = kr1;
    *(u16x8*)((char*)sV + st0) = vr0; *(u16x8*)((char*)sV + st1) = vr1;
    __syncthreads();   // staged tile visible

    // T14: issue tile t+2's global loads now; consumed at next iteration's top.
    if (t + 2 <= qiB) {
      const u16* kg = kgp + (size_t)(t + 2) * 64 * 64;
      const u16* vg = vgp + (t + 2) * 64;
      kr0 = *(const u16x8*)kg; kr1 = *(const u16x8*)(kg + 8);
      vr0 = *(const u16x8*)vg; vr1 = *(const u16x8*)(vg + 8);
    }

    // ---- QK phase: K fragments live ----
    {
      bf16x8 kf[4][2];
#pragma unroll
      for (int ct = 0; ct < 4; ++ct) {
        const char* krow = (const char*)sK + (ct * 16 + l15) * 128;
        kf[ct][0] = *(const bf16x8*)(krow + fo0);
        kf[ct][1] = *(const bf16x8*)(krow + fo1);
      }

#pragma unroll
      for (int s = 0; s < 2; ++s) {
        if (s == 0 && t > qiA) continue;
        const int diag = s ? qiB : qiA;

        // S^T = K Q^T: lane holds S[kv=ct*16+lg*4+i][q=l15]
        f32x4 st[4];
#pragma unroll
        for (int ct = 0; ct < 4; ++ct) {
          f32x4 s4 = {};
          s4 = __builtin_amdgcn_mfma_f32_16x16x32_bf16(kf[ct][0], qa[s][0], s4, 0, 0, 0);
          s4 = __builtin_amdgcn_mfma_f32_16x16x32_bf16(kf[ct][1], qa[s][1], s4, 0, 0, 0);
          st[ct] = s4;
        }

        if (t == diag) {
          const int ql = w * 16 + l15;
#pragma unroll
          for (int ct = 0; ct < 4; ++ct)
#pragma unroll
            for (int i = 0; i < 4; ++i)
              st[ct][i] = (ct * 16 + lg * 4 + i <= ql) ? st[ct][i] : -1e30f;
        }

        // P = exp2(S'), pack, write to this stream's sP; accumulate row-sum
        float ls = 0.f;
        char* prow = s ? prow1 : prow0;
#pragma unroll
        for (int ct = 0; ct < 4; ++ct) {
          float p0 = exp2f(st[ct][0]), p1 = exp2f(st[ct][1]);
          float p2 = exp2f(st[ct][2]), p3 = exp2f(st[ct][3]);
          ls += (p0 + p1) + (p2 + p3);
          u32 lo = (u32)f2bfh(p0) | ((u32)f2bfh(p1) << 16);
          u32 hi = (u32)f2bfh(p2) | ((u32)f2bfh(p3) << 16);
          *(u32x2*)(prow + ((ct * 32 + lg * 8) ^ swzP)) = (u32x2){lo, hi};
        }
        l_s[s] += ls;
      }
    }

    // ---- PV phase: V fragments live ----
    {
      bf16x8 vf[4][2];
#pragma unroll
      for (int ct = 0; ct < 4; ++ct) {
        const char* vrow = (const char*)sV + (ct * 16 + l15) * 128;
        vf[ct][0] = *(const bf16x8*)(vrow + fo0);
        vf[ct][1] = *(const bf16x8*)(vrow + fo1);
      }

#pragma unroll
      for (int s = 0; s < 2; ++s) {
        if (s == 0 && t > qiA) continue;
        const char* prow = s ? prow1 : prow0;
        bf16x8 pa0 = *(const bf16x8*)(prow + ((lg * 16) ^ swzP));
        bf16x8 pa1 = *(const bf16x8*)(prow + ((64 + lg * 16) ^ swzP));
#pragma unroll
        for (int n = 0; n < 4; ++n) {
          acc[s][n] = __builtin_amdgcn_mfma_f32_16x16x32_bf16(pa0, vf[n][0], acc[s][n], 0, 0, 0);
          acc[s][n] = __builtin_amdgcn_mfma_f32_16x16x32_bf16(pa1, vf[n][1], acc[s][n], 0, 0, 0);
        }
      }
    }
  }

  // epilogue: reduce l across lg-groups, write unnormalized partials.
#pragma unroll
  for (int s = 0; s < 2; ++s) {
    float lv = l_s[s];
    lv += __shfl_xor(lv, 16);
    lv += __shfl_xor(lv, 32);
    if (lg == 0) {
      int qrow = q0s[s] + w * 16 + l15;
      lP[((size_t)z * 4096 + b * 2048 + qrow) * 16 + h] = lv;
    }
#pragma unroll
    for (int i = 0; i < 4; ++i) {
      int srowg = q0s[s] + w * 16 + lg * 4 + i;
      size_t rowbase = (size_t)z * 4096 + b * 2048 + srowg;
      u16* orow = accP + rowbase * 1024 + h * 64 + l15;
#pragma unroll
      for (int n = 0; n < 4; ++n) orow[n * 16] = f2bfh(acc[s][n][i]);
    }
  }
}

// ---------------- combine KV-split partials: O = (a0+a1)/(l0+l1) * gate ----------------
__global__ __launch_bounds__(256) void attn_combine(const u16* __restrict__ accP, const float* __restrict__ lP,
                                                    const float* __restrict__ gate, u16* __restrict__ attnh) {
  const size_t e = ((size_t)blockIdx.x * 256 + threadIdx.x) * 8;
  const int token = (int)(e >> 10);
  const int h = (int)((e >> 6) & 15);
  u16x8 a0 = *(const u16x8*)(accP + e);
  u16x8 a1 = *(const u16x8*)(accP + ((size_t)4096 << 10) + e);
  float l0 = lP[(size_t)token * 16 + h];
  float l1 = lP[(size_t)4096 * 16 + (size_t)token * 16 + h];
  float g = gate[(size_t)token * 16 + h] / (l0 + l1);
  u16x8 o;
#pragma unroll
  for (int j = 0; j < 8; ++j) o[j] = f2bfh((bf2f(a0[j]) + bf2f(a1[j])) * g);
  *(u16x8*)(attnh + e) = o;
}

// ---------------- launch ----------------
extern "C" void kernel_launch(void* const* d_in, const int* in_sizes, int n_in,
                              void* d_out, int out_size, void* d_ws, size_t ws_size,
                              hipStream_t stream) {
  const float* x  = (const float*)d_in[0];
  const float* Wf = (const float*)d_in[1];
  const float* qw = (const float*)d_in[2];
  const float* kw = (const float*)d_in[3];
  const float* gw = (const float*)d_in[4];
  float* out = (float*)d_out;

  char* ws = (char*)d_ws;
  size_t off = 0;
  auto alloc = [&](size_t bytes) { void* p = ws + off; off += (bytes + 255) & ~(size_t)255; return p; };

  u16*   xb   = (u16*)alloc((size_t)4096 * 1024 * 2);
  u16*   wb   = (u16*)alloc((size_t)2560 * 1024 * 2);
  float* qkv  = (float*)alloc((size_t)4096 * 1536 * 4);
  u16*   Qb   = (u16*)alloc((size_t)2 * 16 * 2048 * 64 * 2);
  u16*   Kb   = (u16*)alloc((size_t)2 * 4 * 2048 * 64 * 2);
  u16*   Vb   = (u16*)alloc((size_t)2 * 4 * 2048 * 64 * 2);
  u16*   Vtb  = (u16*)alloc((size_t)2 * 4 * 2048 * 64 * 2);
  float* gate = (float*)alloc((size_t)2 * 2048 * 16 * 4);
  float* lP   = (float*)alloc((size_t)2 * 4096 * 16 * 4);
  // partial acc (16 MB) aliases qkv (24 MB, dead after norm_rope_gate);
  // attnh (8 MB) aliases xb (dead after the QKV GEMM).
  u16* accP  = (u16*)qkv;
  u16* attnh = xb;

  cvt2_bf16<<<dim3(6656), dim3(256), 0, stream>>>(x, xb, 4096 * 1024 / 4, Wf, wb, 2560 * 1024 / 4);
  gemm_nt<<<dim3(32, 12), dim3(256), 0, stream>>>(xb, wb, qkv, 4096, 1536, 1024);
  norm_rope_gate<<<dim3(1024), dim3(256), 0, stream>>>(qkv, x, qw, kw, gw, Qb, Kb, Vb, gate);
  transpose_v64<<<dim3(32, 8), dim3(256), 0, stream>>>(Vb, Vtb);
  attn_fwd_pair<<<dim3(16, 32, 2), dim3(256), 0, stream>>>(Qb, Kb, Vtb, accP, lP);
  attn_combine<<<dim3(2048), dim3(256), 0, stream>>>(accP, lP, gate, attnh);
  gemm_nt<<<dim3(32, 8), dim3(256), 0, stream>>>(attnh, wb + (size_t)1536 * 1024, out, 4096, 1024, 1024);
}

// Round 11
// 137.036 us; speedup vs baseline: 1.5849x; 1.5849x over previous
//
#include <hip/hip_runtime.h>
#include <math.h>

typedef unsigned short u16;
typedef unsigned int u32;
typedef __bf16 bf16x8 __attribute__((ext_vector_type(8)));
typedef float f32x4 __attribute__((ext_vector_type(4)));
typedef unsigned short u16x8 __attribute__((ext_vector_type(8)));
typedef unsigned int u32x2 __attribute__((ext_vector_type(2)));

static __device__ __forceinline__ u16 f2bf(float f) {
  unsigned int u = __builtin_bit_cast(unsigned int, f);
  u = (u + 0x7FFFu + ((u >> 16) & 1u)) >> 16;
  return (u16)u;
}
static __device__ __forceinline__ float bf2f(u16 u) {
  unsigned int x = ((unsigned int)u) << 16;
  return __builtin_bit_cast(float, x);
}
static __device__ __forceinline__ u16 f2bfh(float f) {
  __bf16 b = (__bf16)f;
  return __builtin_bit_cast(u16, b);
}
static __device__ __forceinline__ void gll16(const u16* g, u16* l) {
  __builtin_amdgcn_global_load_lds((const __attribute__((address_space(1))) u32*)g,
                                   (__attribute__((address_space(3))) u32*)l, 16, 0, 0);
}

// ---------------- fused f32 -> bf16 convert for two buffers ----------------
__global__ __launch_bounds__(256) void cvt2_bf16(const float* __restrict__ a, u16* __restrict__ da, int n4a,
                                                 const float* __restrict__ b, u16* __restrict__ db, int n4b) {
  int idx = blockIdx.x * 256 + threadIdx.x;
  const float* src; u16* dst; int i;
  if (idx < n4a) { src = a; dst = da; i = idx; }
  else { i = idx - n4a; if (i >= n4b) return; src = b; dst = db; }
  float4 v = ((const float4*)src)[i];
  ushort4 r;
  r.x = f2bf(v.x); r.y = f2bf(v.y); r.z = f2bf(v.z); r.w = f2bf(v.w);
  ((ushort4*)dst)[i] = r;
}

// ---------------- bf16 NT GEMM, m97 structure: gll16 staging, linear LDS + swizzled src ----
// 128x128 tile, BK=32, 256 threads (4 waves, each 64x64).
__global__ __launch_bounds__(256) void gemm_nt(const u16* __restrict__ A, const u16* __restrict__ B,
                                               float* __restrict__ C, int M, int N, int K) {
  __shared__ __align__(16) u16 sA[128 * 32];
  __shared__ __align__(16) u16 sB[128 * 32];
  const int tid = threadIdx.x;
  const int w = tid >> 6, lane = tid & 63, l15 = lane & 15;
  const int m0 = blockIdx.x * 128, n0 = blockIdx.y * 128;
  const int wm = (w >> 1) * 64, wn = (w & 1) * 64;

  f32x4 acc[4][4] = {};

  const int pb0 = w * 1024 + lane * 16;
  int srow[2], scol[2];
#pragma unroll
  for (int i = 0; i < 2; ++i) {
    int p = pb0 + i * 4096;
    int row = p >> 6, oo = p & 63;
    int ol = oo ^ (((row >> 1) & 3) << 4);
    srow[i] = row; scol[i] = ol >> 1;
  }
  int aoff[4], boff[4];
  const int kb = (lane >> 4) * 16;
#pragma unroll
  for (int m = 0; m < 4; ++m) {
    int r = wm + m * 16 + l15;
    aoff[m] = r * 64 + (kb ^ (((r >> 1) & 3) << 4));
  }
#pragma unroll
  for (int n = 0; n < 4; ++n) {
    int r = wn + n * 16 + l15;
    boff[n] = r * 64 + (kb ^ (((r >> 1) & 3) << 4));
  }

  for (int k0 = 0; k0 < K; k0 += 32) {
#pragma unroll
    for (int i = 0; i < 2; ++i) {
      int p = pb0 + i * 4096;
      gll16(A + (size_t)(m0 + srow[i]) * K + k0 + scol[i], (u16*)((char*)sA + p));
      gll16(B + (size_t)(n0 + srow[i]) * K + k0 + scol[i], (u16*)((char*)sB + p));
    }
    __syncthreads();
    bf16x8 af[4], bfr[4];
#pragma unroll
    for (int m = 0; m < 4; ++m) af[m] = *(const bf16x8*)((const char*)sA + aoff[m]);
#pragma unroll
    for (int n = 0; n < 4; ++n) bfr[n] = *(const bf16x8*)((const char*)sB + boff[n]);
#pragma unroll
    for (int m = 0; m < 4; ++m)
#pragma unroll
      for (int n = 0; n < 4; ++n)
        acc[m][n] = __builtin_amdgcn_mfma_f32_16x16x32_bf16(af[m], bfr[n], acc[m][n], 0, 0, 0);
    __syncthreads();
  }

#pragma unroll
  for (int m = 0; m < 4; ++m)
#pragma unroll
    for (int i = 0; i < 4; ++i) {
      int gr = m0 + wm + m * 16 + (lane >> 4) * 4 + i;
      float* crow = C + (size_t)gr * N + n0 + wn + l15;
#pragma unroll
      for (int n = 0; n < 4; ++n) crow[n * 16] = acc[m][n][i];
    }
}

// ---------------- RMSNorm + RoPE + V cast + gate ----------------
#define QSCALE 0.18033688011112042f
__global__ __launch_bounds__(256) void norm_rope_gate(const float* __restrict__ qkv, const float* __restrict__ x,
                                                      const float* __restrict__ qw, const float* __restrict__ kw,
                                                      const float* __restrict__ gw,
                                                      u16* __restrict__ Q, u16* __restrict__ Kd,
                                                      u16* __restrict__ V, float* __restrict__ gate) {
  const int t = blockIdx.x * 4 + (threadIdx.x >> 6);
  const int lane = threadIdx.x & 63;
  const int b = t >> 11, s = t & 2047;
  const float* base = qkv + (size_t)t * 1536;
  const int ri = lane >> 1;
  float sn, cs;
  sincosf((float)s * expf(-(float)ri * (9.21034037198f / 32.0f)), &sn, &cs);
  const float qwl = qw[lane], kwl = kw[lane];

  for (int hh = 0; hh < 16; ++hh) {
    float v = base[hh * 64 + lane];
    float ss = v * v;
#pragma unroll
    for (int off = 32; off >= 1; off >>= 1) ss += __shfl_xor(ss, off);
    float r = rsqrtf(ss * (1.0f / 64.0f) + 1.1920929e-7f);
    float xn = v * r * qwl;
    float p = __shfl_xor(xn, 1);
    float outv = ((lane & 1) == 0) ? (xn * cs - p * sn) : (xn * cs + p * sn);
    Q[((size_t)(b * 16 + hh) * 2048 + s) * 64 + lane] = f2bf(outv * QSCALE);
  }
  for (int hh = 0; hh < 4; ++hh) {
    float v = base[1024 + hh * 64 + lane];
    float ss = v * v;
#pragma unroll
    for (int off = 32; off >= 1; off >>= 1) ss += __shfl_xor(ss, off);
    float r = rsqrtf(ss * (1.0f / 64.0f) + 1.1920929e-7f);
    float xn = v * r * kwl;
    float p = __shfl_xor(xn, 1);
    float outv = ((lane & 1) == 0) ? (xn * cs - p * sn) : (xn * cs + p * sn);
    Kd[((size_t)(b * 4 + hh) * 2048 + s) * 64 + lane] = f2bf(outv);
    V[((size_t)(b * 4 + hh) * 2048 + s) * 64 + lane] = f2bf(base[1280 + hh * 64 + lane]);
  }
  if (lane < 16) {
    float g = 0.f;
#pragma unroll
    for (int j = 0; j < 12; ++j) g += x[(size_t)t * 1024 + j] * gw[lane * 12 + j];
    gate[(size_t)t * 16 + lane] = 1.0f / (1.0f + __expf(-g));
  }
}

// ---------------- V transpose: [bh][s][d] -> [bh][d][s] ----------------
__global__ __launch_bounds__(256) void transpose_v64(const u16* __restrict__ V, u16* __restrict__ Vt) {
  __shared__ __align__(16) u16 tile[64][72];
  const int st = blockIdx.x, bh = blockIdx.y;
  const u16* src = V + ((size_t)bh * 2048 + st * 64) * 64;
  u16* dst = Vt + (size_t)bh * 64 * 2048 + st * 64;
  const int t = threadIdx.x;
  const int r = t >> 2, c0 = (t & 3) * 16;
#pragma unroll
  for (int j = 0; j < 2; ++j)
    *(u16x8*)&tile[r][c0 + j * 8] = *(const u16x8*)&src[(size_t)r * 64 + c0 + j * 8];
  __syncthreads();
  u16 tmp[16];
#pragma unroll
  for (int j = 0; j < 16; ++j) tmp[j] = tile[c0 + j][r];
#pragma unroll
  for (int j = 0; j < 2; ++j)
    *(u16x8*)&dst[(size_t)r * 2048 + c0 + j * 8] = *(const u16x8*)&tmp[j * 8];
}

// ---------------- Flash attention: paired q-tiles + 3-way KV split, swapped QK^T ------
// grid (16, B*H, 3). Block (x,bh,z): q-tiles qiA=x, qiB=31-x; KV tiles t ≡ z (mod 3).
// r9 body (dbuf K/V, T14 reg prefetch, 1 barrier/tile, T2 swizzle both sides, no-max
// softmax, per-lane row-sum). Partials (unnormalized bf16 acc, f32 l) per z-zone.
__global__ __launch_bounds__(256) void attn_fwd_pair(const u16* __restrict__ Q, const u16* __restrict__ Kg,
                                                     const u16* __restrict__ Vt,
                                                     u16* __restrict__ accP, float* __restrict__ lP) {
  __shared__ __align__(16) u16 sK[2][64 * 64];  // K[kv][d], double-buffered, swizzled
  __shared__ __align__(16) u16 sV[2][64 * 64];  // Vt[d][kv], swizzled
  __shared__ __align__(16) u16 sP[4][16 * 64];  // per-wave P[q][kv], swizzled

  const int tid = threadIdx.x;
  const int w = tid >> 6, lane = tid & 63;
  const int l15 = lane & 15, lg = lane >> 4;
  const int qiA = blockIdx.x;          // 0..15
  const int qiB = 31 - qiA;            // 31..16
  const int z = blockIdx.z;            // 0..2
  const int bh = blockIdx.y, b = bh >> 4, h = bh & 15, kvh = h >> 2;

  const u16* Qp = Q + (size_t)(b * 16 + h) * 2048 * 64;
  const u16* Kp = Kg + (size_t)(b * 4 + kvh) * 2048 * 64;
  const u16* Vp = Vt + (size_t)(b * 4 + kvh) * 64 * 2048;

  const int q0s[2] = {qiA * 64, qiB * 64};
  bf16x8 qa[2][2];
#pragma unroll
  for (int s = 0; s < 2; ++s) {
    const u16* qrow = Qp + (size_t)(q0s[s] + w * 16 + l15) * 64 + lg * 8;
    qa[s][0] = *(const bf16x8*)qrow;
    qa[s][1] = *(const bf16x8*)(qrow + 32);
  }

  f32x4 acc[2][4] = {};
  float l_s[2] = {0.f, 0.f};

  // staging addresses: global linear; LDS swizzled
  const int srw = tid >> 2;                       // 0..63 rows
  const int scb = (tid & 3) * 32;                 // byte col base in row (128 B rows)
  const int swzS = (srw & 7) << 4;
  const int st0 = srw * 128 + (scb ^ swzS);
  const int st1 = srw * 128 + ((scb + 16) ^ swzS);
  const u16* kgp = Kp + (size_t)srw * 64 + (tid & 3) * 16;
  const u16* vgp = Vp + (size_t)srw * 2048 + (tid & 3) * 16;

  // fragment read byte offsets (swizzle row&7 == l15&7 for rows ct*16+l15)
  const int swzF = (l15 & 7) << 4;
  const int fo0 = (lg * 16) ^ swzF;
  const int fo1 = (64 + lg * 16) ^ swzF;

  // prologue: stage tile z into buffer 0
  u16x8 kr0 = *(const u16x8*)(kgp + (size_t)z * 64 * 64), kr1 = *(const u16x8*)(kgp + (size_t)z * 64 * 64 + 8);
  u16x8 vr0 = *(const u16x8*)(vgp + z * 64),              vr1 = *(const u16x8*)(vgp + z * 64 + 8);
  *(u16x8*)((char*)sK[0] + st0) = kr0; *(u16x8*)((char*)sK[0] + st1) = kr1;
  *(u16x8*)((char*)sV[0] + st0) = vr0; *(u16x8*)((char*)sV[0] + st1) = vr1;
  __syncthreads();

  int it = 0;
  for (int t = z; t <= qiB; t += 3, ++it) {
    const int buf = it & 1;

    // T14: issue tile t+3's global loads now; consume after compute.
    if (t + 3 <= qiB) {
      const u16* kg = kgp + (size_t)(t + 3) * 64 * 64;
      const u16* vg = vgp + (t + 3) * 64;
      kr0 = *(const u16x8*)kg; kr1 = *(const u16x8*)(kg + 8);
      vr0 = *(const u16x8*)vg; vr1 = *(const u16x8*)(vg + 8);
    }

    // shared K / V fragments (read once, used by both streams)
    bf16x8 kf[4][2], vf[4][2];
#pragma unroll
    for (int ct = 0; ct < 4; ++ct) {
      const char* krow = (const char*)sK[buf] + (ct * 16 + l15) * 128;
      const char* vrow = (const char*)sV[buf] + (ct * 16 + l15) * 128;
      kf[ct][0] = *(const bf16x8*)(krow + fo0);
      kf[ct][1] = *(const bf16x8*)(krow + fo1);
      vf[ct][0] = *(const bf16x8*)(vrow + fo0);
      vf[ct][1] = *(const bf16x8*)(vrow + fo1);
    }

#pragma unroll
    for (int s = 0; s < 2; ++s) {
      if (s == 0 && t > qiA) continue;     // stream A done (uniform branch)
      const int diag = s ? qiB : qiA;

      // S^T = K Q^T: lane holds S[kv=ct*16+lg*4+i][q=l15]
      f32x4 st[4];
#pragma unroll
      for (int ct = 0; ct < 4; ++ct) {
        f32x4 s4 = {};
        s4 = __builtin_amdgcn_mfma_f32_16x16x32_bf16(kf[ct][0], qa[s][0], s4, 0, 0, 0);
        s4 = __builtin_amdgcn_mfma_f32_16x16x32_bf16(kf[ct][1], qa[s][1], s4, 0, 0, 0);
        st[ct] = s4;
      }

      if (t == diag) {
        const int ql = w * 16 + l15;
#pragma unroll
        for (int ct = 0; ct < 4; ++ct)
#pragma unroll
          for (int i = 0; i < 4; ++i)
            st[ct][i] = (ct * 16 + lg * 4 + i <= ql) ? st[ct][i] : -1e30f;
      }

      // P = exp2(S'), pack pairs, accumulate per-lane row-sum (q=l15)
      float ls = 0.f;
      const int swzP = (l15 & 7) << 4;
      char* prow = (char*)sP[w] + l15 * 128;
#pragma unroll
      for (int ct = 0; ct < 4; ++ct) {
        float p0 = exp2f(st[ct][0]), p1 = exp2f(st[ct][1]);
        float p2 = exp2f(st[ct][2]), p3 = exp2f(st[ct][3]);
        ls += (p0 + p1) + (p2 + p3);
        u32 lo = (u32)f2bfh(p0) | ((u32)f2bfh(p1) << 16);
        u32 hi = (u32)f2bfh(p2) | ((u32)f2bfh(p3) << 16);
        *(u32x2*)(prow + ((ct * 32 + lg * 8) ^ swzP)) = (u32x2){lo, hi};
      }
      l_s[s] += ls;

      // read P as A-fragments (wave-internal; compiler-ordered lgkmcnt); 16B aligned
      bf16x8 pa0 = *(const bf16x8*)(prow + ((lg * 16) ^ swzP));
      bf16x8 pa1 = *(const bf16x8*)(prow + ((64 + lg * 16) ^ swzP));

#pragma unroll
      for (int n = 0; n < 4; ++n) {
        acc[s][n] = __builtin_amdgcn_mfma_f32_16x16x32_bf16(pa0, vf[n][0], acc[s][n], 0, 0, 0);
        acc[s][n] = __builtin_amdgcn_mfma_f32_16x16x32_bf16(pa1, vf[n][1], acc[s][n], 0, 0, 0);
      }
    }

    if (t + 3 <= qiB) {
      *(u16x8*)((char*)sK[buf ^ 1] + st0) = kr0; *(u16x8*)((char*)sK[buf ^ 1] + st1) = kr1;
      *(u16x8*)((char*)sV[buf ^ 1] + st0) = vr0; *(u16x8*)((char*)sV[buf ^ 1] + st1) = vr1;
    }
    __syncthreads();
  }

  // epilogue: reduce l across lg-groups (lanes l15, l15+16, +32, +48), write partials.
#pragma unroll
  for (int s = 0; s < 2; ++s) {
    float lv = l_s[s];
    lv += __shfl_xor(lv, 16);
    lv += __shfl_xor(lv, 32);
    if (lg == 0) {
      int qrow = q0s[s] + w * 16 + l15;
      lP[((size_t)z * 4096 + b * 2048 + qrow) * 16 + h] = lv;
    }
#pragma unroll
    for (int i = 0; i < 4; ++i) {
      int srowg = q0s[s] + w * 16 + lg * 4 + i;
      size_t rowbase = (size_t)z * 4096 + b * 2048 + srowg;
      u16* orow = accP + rowbase * 1024 + h * 64 + l15;
#pragma unroll
      for (int n = 0; n < 4; ++n) orow[n * 16] = f2bfh(acc[s][n][i]);
    }
  }
}

// ---------------- combine 3-way KV-split partials: O = (a0+a1+a2)/(l0+l1+l2) * gate ------
__global__ __launch_bounds__(256) void attn_combine(const u16* __restrict__ accP, const float* __restrict__ lP,
                                                    const float* __restrict__ gate, u16* __restrict__ attnh) {
  const size_t zstride = (size_t)4096 << 10;   // elements per z-zone
  const size_t e = ((size_t)blockIdx.x * 256 + threadIdx.x) * 8;
  const int token = (int)(e >> 10);
  const int h = (int)((e >> 6) & 15);
  u16x8 a0 = *(const u16x8*)(accP + e);
  u16x8 a1 = *(const u16x8*)(accP + zstride + e);
  u16x8 a2 = *(const u16x8*)(accP + 2 * zstride + e);
  const size_t li = (size_t)token * 16 + h;
  float l = lP[li] + lP[(size_t)4096 * 16 + li] + lP[(size_t)2 * 4096 * 16 + li];
  float g = gate[li] / l;
  u16x8 o;
#pragma unroll
  for (int j = 0; j < 8; ++j) o[j] = f2bfh((bf2f(a0[j]) + bf2f(a1[j]) + bf2f(a2[j])) * g);
  *(u16x8*)(attnh + e) = o;
}

// ---------------- launch ----------------
extern "C" void kernel_launch(void* const* d_in, const int* in_sizes, int n_in,
                              void* d_out, int out_size, void* d_ws, size_t ws_size,
                              hipStream_t stream) {
  const float* x  = (const float*)d_in[0];
  const float* Wf = (const float*)d_in[1];
  const float* qw = (const float*)d_in[2];
  const float* kw = (const float*)d_in[3];
  const float* gw = (const float*)d_in[4];
  float* out = (float*)d_out;

  char* ws = (char*)d_ws;
  size_t off = 0;
  auto alloc = [&](size_t bytes) { void* p = ws + off; off += (bytes + 255) & ~(size_t)255; return p; };

  u16*   xb   = (u16*)alloc((size_t)4096 * 1024 * 2);
  u16*   wb   = (u16*)alloc((size_t)2560 * 1024 * 2);
  float* qkv  = (float*)alloc((size_t)4096 * 1536 * 4);
  u16*   Qb   = (u16*)alloc((size_t)2 * 16 * 2048 * 64 * 2);
  u16*   Kb   = (u16*)alloc((size_t)2 * 4 * 2048 * 64 * 2);
  u16*   Vb   = (u16*)alloc((size_t)2 * 4 * 2048 * 64 * 2);
  u16*   Vtb  = (u16*)alloc((size_t)2 * 4 * 2048 * 64 * 2);
  float* gate = (float*)alloc((size_t)2 * 2048 * 16 * 4);
  float* lP   = (float*)alloc((size_t)3 * 4096 * 16 * 4);
  // partial acc (3 zones x 8 MB = 25.17 MB) aliases qkv (25.17 MB, dead after
  // norm_rope_gate); attnh (8 MB) aliases xb (dead after the QKV GEMM).
  u16* accP  = (u16*)qkv;
  u16* attnh = xb;

  cvt2_bf16<<<dim3(6656), dim3(256), 0, stream>>>(x, xb, 4096 * 1024 / 4, Wf, wb, 2560 * 1024 / 4);
  gemm_nt<<<dim3(32, 12), dim3(256), 0, stream>>>(xb, wb, qkv, 4096, 1536, 1024);
  norm_rope_gate<<<dim3(1024), dim3(256), 0, stream>>>(qkv, x, qw, kw, gw, Qb, Kb, Vb, gate);
  transpose_v64<<<dim3(32, 8), dim3(256), 0, stream>>>(Vb, Vtb);
  attn_fwd_pair<<<dim3(16, 32, 3), dim3(256), 0, stream>>>(Qb, Kb, Vtb, accP, lP);
  attn_combine<<<dim3(2048), dim3(256), 0, stream>>>(accP, lP, gate, attnh);
  gemm_nt<<<dim3(32, 8), dim3(256), 0, stream>>>(attnh, wb + (size_t)1536 * 1024, out, 4096, 1024, 1024);
}